// Round 1
// baseline (2734.937 us; speedup 1.0000x reference)
//
#include <hip/hip_runtime.h>
#include <hip/hip_cooperative_groups.h>
#include <stdint.h>

typedef unsigned int uint;
typedef unsigned long long ull;
typedef __attribute__((ext_vector_type(8))) short short8;
typedef __attribute__((ext_vector_type(4))) float f32x4;
typedef __attribute__((ext_vector_type(4))) uint uintx4;

#define AS1 __attribute__((address_space(1)))
#define AS3 __attribute__((address_space(3)))

__device__ __forceinline__ unsigned short f2bf(float f) {
  uint u = __float_as_uint(f);
  u += 0x7fffu + ((u >> 16) & 1u);
  return (unsigned short)(u >> 16);
}
__device__ __forceinline__ float bfl(unsigned short s) {
  return __uint_as_float(((uint)s) << 16);
}

// ---------------- build kernels ----------------

// A[dir][m=t*8+b][e] = bf16(x or x_rev), 2 x 4096 x 1024
__global__ __launch_bounds__(256) void k_build_A(const float* __restrict__ x,
                                                 const int* __restrict__ lengths,
                                                 unsigned short* __restrict__ A) {
  int idx = blockIdx.x * 256 + threadIdx.x;   // float4 units, 2*1Mi total
  int dir = idx >> 20;
  int r = idx & 1048575;
  int m = r >> 8;
  int e4 = r & 255;
  int t = m >> 3, b = m & 7;
  int st = t;
  if (dir) { int len = lengths[b]; st = (t < len) ? (len - 1 - t) : t; }
  float4 v = *(const float4*)&x[((size_t)b * 512 + st) * 1024 + e4 * 4];
  ushort4 o;
  o.x = f2bf(v.x); o.y = f2bf(v.y); o.z = f2bf(v.z); o.w = f2bf(v.w);
  *(ushort4*)&A[(size_t)dir * 4194304 + (size_t)m * 1024 + e4 * 4] = o;
}

// Wp[dir][j][e] = bf16(W_ih)
__global__ __launch_bounds__(256) void k_cast_wih(const float* __restrict__ Wf,
                                                  const float* __restrict__ Wb,
                                                  unsigned short* __restrict__ Wp) {
  int idx = blockIdx.x * 256 + threadIdx.x;
  int dir = idx >> 20;
  int r = idx & 1048575;
  const float* src = dir ? Wb : Wf;
  float4 v = *(const float4*)&src[(size_t)r * 4];
  ushort4 o;
  o.x = f2bf(v.x); o.y = f2bf(v.y); o.z = f2bf(v.z); o.w = f2bf(v.w);
  *(ushort4*)&Wp[(size_t)dir * 4194304 + (size_t)r * 4] = o;
}

// WF: W_hh in MFMA B-fragment order, per (dir, mc) slice of 32 j-rows.
// gtid = lane(6) | f(6) | mc(7) | dir(1); f = kt*2+nt
// B[n_local = nt*16+(lane&15)][k = kt*32+(lane>>4)*8 + v], v<8
// j = (n_local>>3)*1024 + mc*8 + (n_local&7)
__global__ __launch_bounds__(256) void k_build_wf(const float* __restrict__ Wf,
                                                  const float* __restrict__ Wb,
                                                  unsigned short* __restrict__ WF) {
  int gtid = blockIdx.x * 256 + threadIdx.x;   // 2^20
  int lane = gtid & 63;
  int f    = (gtid >> 6) & 63;
  int mc   = (gtid >> 12) & 127;
  int dir  = (gtid >> 19) & 1;
  int kt = f >> 1, nt = f & 1;
  int n_local = nt * 16 + (lane & 15);
  int j = (n_local >> 3) * 1024 + mc * 8 + (n_local & 7);
  int k0 = kt * 32 + (lane >> 4) * 8;
  const float* src = dir ? Wb : Wf;
  const float* s = &src[(size_t)j * 1024 + k0];
  float4 v0 = *(const float4*)s;
  float4 v1 = *(const float4*)(s + 4);
  ushort4 oa, ob;
  oa.x = f2bf(v0.x); oa.y = f2bf(v0.y); oa.z = f2bf(v0.z); oa.w = f2bf(v0.w);
  ob.x = f2bf(v1.x); ob.y = f2bf(v1.y); ob.z = f2bf(v1.z); ob.w = f2bf(v1.w);
  *(ushort4*)&WF[(size_t)gtid * 8] = oa;
  *(ushort4*)&WF[(size_t)gtid * 8 + 4] = ob;
}

// WET[e][k] = W_emit[k][e]  (fp32)
__global__ __launch_bounds__(256) void k_build_wet(const float* __restrict__ We,
                                                   float* __restrict__ WET) {
  int idx = blockIdx.x * 256 + threadIdx.x;  // 32768
  int e = idx >> 4, k = idx & 15;
  WET[(size_t)e * 16 + k] = We[(size_t)k * 2048 + e];
}

// ---------------- projection GEMM (bf16 MFMA): P[dir][m][j] = A @ W_ih^T + b ----------------
__global__ __launch_bounds__(256) void k_proj(const unsigned short* __restrict__ A,
                                              const unsigned short* __restrict__ Wp,
                                              const float* __restrict__ bfv,
                                              const float* __restrict__ bbv,
                                              unsigned short* __restrict__ P) {
  const int dir = blockIdx.z;
  const unsigned short* Ad = A + (size_t)dir * 4194304;
  const unsigned short* Wd = Wp + (size_t)dir * 4194304;
  const float* bias = dir ? bbv : bfv;
  unsigned short* Pd = P + (size_t)dir * 16777216;
  const int bm = blockIdx.x * 128;
  const int bn = blockIdx.y * 128;
  __shared__ unsigned short As[128 * 32];
  __shared__ unsigned short Bs[128 * 32];
  const int tid = threadIdx.x;
  const int w = tid >> 6, lane = tid & 63;
  const int wm = (w >> 1) * 64, wn = (w & 1) * 64;
  const int q = lane >> 4, rr = lane & 15;

  f32x4 acc[4][4];
#pragma unroll
  for (int i = 0; i < 4; ++i)
#pragma unroll
    for (int j = 0; j < 4; ++j) acc[i][j] = (f32x4){0.f, 0.f, 0.f, 0.f};

  for (int k0 = 0; k0 < 1024; k0 += 32) {
#pragma unroll
    for (int i = 0; i < 2; ++i) {
      int c = i * 256 + tid;
      int row = c >> 2, col = (c & 3) * 8;
      const unsigned short* ga = Ad + (size_t)(bm + row) * 1024 + k0 + col;
      const unsigned short* gb = Wd + (size_t)(bn + row) * 1024 + k0 + col;
      __builtin_amdgcn_global_load_lds((const AS1 void*)ga,
                                       (AS3 void*)&As[(i * 256 + w * 64) * 8], 16, 0, 0);
      __builtin_amdgcn_global_load_lds((const AS1 void*)gb,
                                       (AS3 void*)&Bs[(i * 256 + w * 64) * 8], 16, 0, 0);
    }
    __syncthreads();
    short8 av[4], bv[4];
#pragma unroll
    for (int i = 0; i < 4; ++i)
      av[i] = *(const short8*)&As[(wm + i * 16 + rr) * 32 + q * 8];
#pragma unroll
    for (int j = 0; j < 4; ++j)
      bv[j] = *(const short8*)&Bs[(wn + j * 16 + rr) * 32 + q * 8];
#pragma unroll
    for (int i = 0; i < 4; ++i)
#pragma unroll
      for (int j = 0; j < 4; ++j)
        acc[i][j] = __builtin_amdgcn_mfma_f32_16x16x32_bf16(av[i], bv[j], acc[i][j], 0, 0, 0);
    __syncthreads();
  }
#pragma unroll
  for (int i = 0; i < 4; ++i)
#pragma unroll
    for (int j = 0; j < 4; ++j)
#pragma unroll
      for (int reg = 0; reg < 4; ++reg) {
        int row = wm + i * 16 + q * 4 + reg;
        int col = wn + j * 16 + rr;
        float vv = acc[i][j][reg] + bias[bn + col];
        Pd[(size_t)(bm + row) * 4096 + bn + col] = f2bf(vv);
      }
}

// ---------------- persistent recurrence: R10 — self-validating tagged publish ----------
// 256 blocks: dir = bid&1, mc = bid>>1. 32 j-rows (4 gates x 8 hidden) per block.
// Publish format: hg[buf][dir][mc*64 + lane] = u32( bf16(h) << 16 | (t+1) ).
//   - 4-B store is naturally atomic at the coherence point -> data IS the flag.
//   - producer: one relaxed agent store per lane, NO waitcnt ack, NO separate flag.
//   - consumer: per-thread sparse spin on 1 sentinel word of its 32-word slice,
//     then one batched 128-B dwordx4 x8 sc0 sc1 load + verify all 32 tags
//     (re-load only on rare partial visibility). Detect+transfer merge ~1.5 RTT.
// Buffer reuse safety (2-deep ping-pong, tag = t+1): producers overwrite buf[t&1]
// at step t only after verifying all tags==t, which requires every block's verify
// of step t-1 (reader of buf[t&1]'s old content) to have exited. hg is zeroed per
// launch so stale tags from a previous replay cannot alias.
// Waves 1,2: MFMA with W_hh B-fragments hoisted to 128 VGPRs (loop-invariant) —
// no w_lds, 32 fewer ds_read_b128 per wave per step.
// Waves 0,3: duplicate 1-cell epilogue; wave 0 publishes, wave 3 writes h_seq.
__global__ __launch_bounds__(256, 1) void k_rec(const unsigned short* __restrict__ WF,
                                                const unsigned short* __restrict__ P,
                                                const int* __restrict__ lengths,
                                                uint* __restrict__ hg,     // [2buf][2dir][8192] u32
                                                float* __restrict__ h_seq) {
  __shared__ __align__(16) unsigned short h_lds[8 * 1032];   // [batch][k] stride 1032
  __shared__ float gl[32 * 9];

  const int bid = blockIdx.x;
  const int dir = bid & 1;
  const int mc  = bid >> 1;
  const int tid = threadIdx.x;
  const int w   = tid >> 6, lane = tid & 63;
  const int q   = lane >> 4;
  const int nt  = w - 1;                 // waves 1,2 -> n-tiles 0,1
  const bool mfma_w = (w == 1) || (w == 2);

  // ---- hoist W_hh B-fragments into registers (loop-invariant): 32 x short8 ----
  short8 wfrag[32];
  if (mfma_w) {
    const unsigned short* wbase =
        WF + (size_t)(dir * 128 + mc) * 32768 + nt * 512 + lane * 8;
#pragma unroll
    for (int kt = 0; kt < 32; ++kt)
      wfrag[kt] = *(const short8*)&wbase[(size_t)kt * 1024];
  }

  // epilogue identity (waves 0 and 3): cell (b = lane>>3, r = lane&7)
  const bool epi = (w == 0) || (w == 3);
  const int eb = lane >> 3, er = lane & 7;
  const int len_e = epi ? lengths[eb] : 0;
  float c_reg = 0.f, h_reg = 0.f;

  // consumer slice identity: thread owns words [tid*32, tid*32+32) of the 8192-word
  // dir-buffer -> producer pmc = tid>>1, batch rows peb0..peb0+3
  const int peb0 = (tid & 1) * 4;
  const int pmc  = tid >> 1;

  for (int t = 0; t < 512; ++t) {
    // ---- P prefetch (raw ushorts; converted only in epilogue) ----
    unsigned short pv0 = 0, pv1 = 0, pv2 = 0, pv3 = 0;
    if (epi) {
      const unsigned short* prow =
          P + (size_t)dir * 16777216 + (size_t)(t * 8 + eb) * 4096 + mc * 8 + er;
      pv0 = prow[0]; pv1 = prow[1024]; pv2 = prow[2048]; pv3 = prow[3072];
    }

    if (t > 0) {
      const uint need = (uint)t;   // tag published with h[t-1]
      const uint* hb = hg + (size_t)(((t - 1) & 1) * 2 + dir) * 8192 + tid * 32;

      // ---- sparse spin: each thread waits on the first word of its slice ----
      {
        uint v;
        do {
          asm volatile("global_load_dword %0, %1, off sc0 sc1\n\t"
                       "s_waitcnt vmcnt(0)"
                       : "=&v"(v) : "v"(hb) : "memory");
        } while ((v ^ need) & 0xffffu);
      }

      // ---- batched load of the full 128-B slice + tag verify (rarely loops) ----
      uintx4 r0, r1, r2, r3, r4, r5, r6, r7;
      for (;;) {
        asm volatile(
            "global_load_dwordx4 %0, %8, off sc0 sc1\n\t"
            "global_load_dwordx4 %1, %8, off offset:16 sc0 sc1\n\t"
            "global_load_dwordx4 %2, %8, off offset:32 sc0 sc1\n\t"
            "global_load_dwordx4 %3, %8, off offset:48 sc0 sc1\n\t"
            "global_load_dwordx4 %4, %8, off offset:64 sc0 sc1\n\t"
            "global_load_dwordx4 %5, %8, off offset:80 sc0 sc1\n\t"
            "global_load_dwordx4 %6, %8, off offset:96 sc0 sc1\n\t"
            "global_load_dwordx4 %7, %8, off offset:112 sc0 sc1\n\t"
            "s_waitcnt vmcnt(0)"
            : "=&v"(r0), "=&v"(r1), "=&v"(r2), "=&v"(r3),
              "=&v"(r4), "=&v"(r5), "=&v"(r6), "=&v"(r7)
            : "v"(hb)
            : "memory");
        uint d = (r0.x ^ need) | (r0.y ^ need) | (r0.z ^ need) | (r0.w ^ need);
        d |= (r1.x ^ need) | (r1.y ^ need) | (r1.z ^ need) | (r1.w ^ need);
        d |= (r2.x ^ need) | (r2.y ^ need) | (r2.z ^ need) | (r2.w ^ need);
        d |= (r3.x ^ need) | (r3.y ^ need) | (r3.z ^ need) | (r3.w ^ need);
        d |= (r4.x ^ need) | (r4.y ^ need) | (r4.z ^ need) | (r4.w ^ need);
        d |= (r5.x ^ need) | (r5.y ^ need) | (r5.z ^ need) | (r5.w ^ need);
        d |= (r6.x ^ need) | (r6.y ^ need) | (r6.z ^ need) | (r6.w ^ need);
        d |= (r7.x ^ need) | (r7.y ^ need) | (r7.z ^ need) | (r7.w ^ need);
        if (__ballot((d & 0xffffu) != 0u) == 0ull) break;
      }

      // ---- extract bf16 (high halves) and place into h_lds[batch][k] ----
      {
        uintx4 o;
        o.x = (r0.x >> 16) | (r0.y & 0xffff0000u);
        o.y = (r0.z >> 16) | (r0.w & 0xffff0000u);
        o.z = (r1.x >> 16) | (r1.y & 0xffff0000u);
        o.w = (r1.z >> 16) | (r1.w & 0xffff0000u);
        *(uintx4*)&h_lds[(peb0 + 0) * 1032 + pmc * 8] = o;
        o.x = (r2.x >> 16) | (r2.y & 0xffff0000u);
        o.y = (r2.z >> 16) | (r2.w & 0xffff0000u);
        o.z = (r3.x >> 16) | (r3.y & 0xffff0000u);
        o.w = (r3.z >> 16) | (r3.w & 0xffff0000u);
        *(uintx4*)&h_lds[(peb0 + 1) * 1032 + pmc * 8] = o;
        o.x = (r4.x >> 16) | (r4.y & 0xffff0000u);
        o.y = (r4.z >> 16) | (r4.w & 0xffff0000u);
        o.z = (r5.x >> 16) | (r5.y & 0xffff0000u);
        o.w = (r5.z >> 16) | (r5.w & 0xffff0000u);
        *(uintx4*)&h_lds[(peb0 + 2) * 1032 + pmc * 8] = o;
        o.x = (r6.x >> 16) | (r6.y & 0xffff0000u);
        o.y = (r6.z >> 16) | (r6.w & 0xffff0000u);
        o.z = (r7.x >> 16) | (r7.y & 0xffff0000u);
        o.w = (r7.z >> 16) | (r7.w & 0xffff0000u);
        *(uintx4*)&h_lds[(peb0 + 3) * 1032 + pmc * 8] = o;
      }
      __syncthreads();                                   // B2: h_lds ready
      // ---- MFMA: waves 1,2 with 4 independent accumulators, W from regs ----
      if (mfma_w) {
        f32x4 a0 = (f32x4){0.f, 0.f, 0.f, 0.f}, a1 = a0, a2 = a0, a3 = a0;
        const unsigned short* hrow = &h_lds[(lane & 7) * 1032 + q * 8];
#pragma unroll
        for (int kt = 0; kt < 32; kt += 4) {
          short8 v0 = *(const short8*)&hrow[(kt + 0) * 32];
          short8 v1 = *(const short8*)&hrow[(kt + 1) * 32];
          short8 v2 = *(const short8*)&hrow[(kt + 2) * 32];
          short8 v3 = *(const short8*)&hrow[(kt + 3) * 32];
          a0 = __builtin_amdgcn_mfma_f32_16x16x32_bf16(v0, wfrag[kt + 0], a0, 0, 0, 0);
          a1 = __builtin_amdgcn_mfma_f32_16x16x32_bf16(v1, wfrag[kt + 1], a1, 0, 0, 0);
          a2 = __builtin_amdgcn_mfma_f32_16x16x32_bf16(v2, wfrag[kt + 2], a2, 0, 0, 0);
          a3 = __builtin_amdgcn_mfma_f32_16x16x32_bf16(v3, wfrag[kt + 3], a3, 0, 0, 0);
        }
        a0 += a1; a2 += a3; a0 += a2;
        if (q < 2) {
#pragma unroll
          for (int reg = 0; reg < 4; ++reg)
            gl[(nt * 16 + (lane & 15)) * 9 + q * 4 + reg] = a0[reg];
        }
      }
    }
    __syncthreads();                                     // B3: gl ready (or t==0)

    // ---- epilogue: waves 0 and 3 compute identical cells ----
    if (epi) {
      if (t < len_e) {
        float g0 = (t > 0) ? gl[(0 * 8 + er) * 9 + eb] : 0.f;
        float g1 = (t > 0) ? gl[(1 * 8 + er) * 9 + eb] : 0.f;
        float g2 = (t > 0) ? gl[(2 * 8 + er) * 9 + eb] : 0.f;
        float g3 = (t > 0) ? gl[(3 * 8 + er) * 9 + eb] : 0.f;
        float gi = g0 + bfl(pv0);
        float gf = g1 + bfl(pv1);
        float gg = g2 + bfl(pv2);
        float go = g3 + bfl(pv3);
        float si = 1.f / (1.f + __expf(-gi));
        float sf = 1.f / (1.f + __expf(-gf));
        float so = 1.f / (1.f + __expf(-go));
        float tg = tanhf(gg);
        float cn = sf * c_reg + si * tg;
        float hn = so * tanhf(cn);
        c_reg = cn;
        h_reg = hn;
      }
      if (w == 3) {
        if (t < len_e)
          h_seq[((size_t)(dir * 512 + t) * 8 + eb) * 1024 + mc * 8 + er] = h_reg;
      } else {
        // wave 0: one self-validating tagged store per lane, fire-and-forget.
        uint word = ((uint)f2bf(h_reg) << 16) | (uint)(t + 1);
        uint* dst = hg + (size_t)((t & 1) * 2 + dir) * 8192 + mc * 64 + lane;
        __hip_atomic_store(dst, word, __ATOMIC_RELAXED, __HIP_MEMORY_SCOPE_AGENT);
      }
    }
  }
}

// ---------------- emissions: emit[t*8+b][k] = [hf, hb(rev)] @ W_emit^T + b_emit ----------------
__global__ __launch_bounds__(64) void k_emit(const float* __restrict__ h_seq,
    const float* __restrict__ WET, const float* __restrict__ b_emit,
    const int* __restrict__ lengths, float* __restrict__ emit) {
  __shared__ float hl[4][2048];
  const int tid = threadIdx.x;
  const int p0 = blockIdx.x * 4;
  for (int i = 0; i < 32; ++i) {
    int idx = tid + i * 64;          // float4 index 0..2047
    int pl = idx >> 9;
    int r = idx & 511;
    int p = p0 + pl;
    int t = p >> 3, b = p & 7;
    int len = lengths[b];
    float4 v = make_float4(0.f, 0.f, 0.f, 0.f);
    if (t < len) {
      if (r < 256) {
        v = *(const float4*)&h_seq[((size_t)t * 8 + b) * 1024 + r * 4];
      } else {
        int tr = len - 1 - t;
        v = *(const float4*)&h_seq[((size_t)(512 + tr) * 8 + b) * 1024 + (r - 256) * 4];
      }
    }
    *(float4*)&hl[pl][r * 4] = v;
  }
  __syncthreads();
  const int k = tid & 15, pl = tid >> 4;
  const int p = p0 + pl;
  const int t = p >> 3, b = p & 7;
  const int len = lengths[b];
  float acc = 0.f;
  if (t < len) {
    const float* hrow = hl[pl];
#pragma unroll 4
    for (int e4 = 0; e4 < 512; ++e4) {
      float4 h4 = *(const float4*)&hrow[e4 * 4];
      acc += h4.x * WET[(e4 * 4 + 0) * 16 + k]
           + h4.y * WET[(e4 * 4 + 1) * 16 + k]
           + h4.z * WET[(e4 * 4 + 2) * 16 + k]
           + h4.w * WET[(e4 * 4 + 3) * 16 + k];
    }
    acc += b_emit[k];
  }
  emit[(size_t)p * 16 + k] = (t < len) ? acc : 0.f;
}

// ---------------- CRF: gold score + forward algorithm, out[b] = logZ - total ----------------
__global__ __launch_bounds__(128) void k_crf(const float* __restrict__ emit,
    const int* __restrict__ tags, const int* __restrict__ lengths,
    const float* __restrict__ trans, float* __restrict__ out) {
  __shared__ float d_lds[8][17];
  __shared__ float tot[8][17];
  __shared__ float totb[8];
  const int tid = threadIdx.x;
  const int b = tid >> 4, k = tid & 15;
  const int len = lengths[b];

  float part = 0.f;
  for (int t = k; t < 512; t += 16) {
    if (t < len) {
      int tg = tags[b * 512 + t];
      part += emit[((size_t)t * 8 + b) * 16 + tg];
      if (t >= 1) part += trans[tags[b * 512 + t - 1] * 16 + tg];
    }
  }
  tot[b][k] = part;

  float trc[16];
#pragma unroll
  for (int i = 0; i < 16; ++i) trc[i] = trans[i * 16 + k];
  d_lds[b][k] = emit[b * 16 + k];
  __syncthreads();
  if (k == 0) {
    float s = 0.f;
    for (int i = 0; i < 16; ++i) s += tot[b][i];
    totb[b] = s;
  }
  __syncthreads();

  for (int t = 1; t < 512; ++t) {
    float nd = 0.f;
    bool upd = (t < len);
    if (upd) {
      float mx = -3.0e38f;
      float v[16];
#pragma unroll
      for (int i = 0; i < 16; ++i) { v[i] = d_lds[b][i] + trc[i]; mx = fmaxf(mx, v[i]); }
      float s = 0.f;
#pragma unroll
      for (int i = 0; i < 16; ++i) s += __expf(v[i] - mx);
      nd = mx + __logf(s) + emit[((size_t)t * 8 + b) * 16 + k];
    }
    __syncthreads();
    if (upd) d_lds[b][k] = nd;
    __syncthreads();
  }

  if (k == 0) {
    float mx = -3.0e38f;
    for (int i = 0; i < 16; ++i) mx = fmaxf(mx, d_lds[b][i]);
    float s = 0.f;
    for (int i = 0; i < 16; ++i) s += __expf(d_lds[b][i] - mx);
    out[b] = (mx + __logf(s)) - totb[b];
  }
}

extern "C" void kernel_launch(void* const* d_in, const int* in_sizes, int n_in,
                              void* d_out, int out_size, void* d_ws, size_t ws_size,
                              hipStream_t stream) {
  const float* x       = (const float*)d_in[0];
  const int*   tags    = (const int*)d_in[1];
  const int*   lengths = (const int*)d_in[2];
  const float* W_ih_f  = (const float*)d_in[3];
  const float* W_hh_f  = (const float*)d_in[4];
  const float* b_f     = (const float*)d_in[5];
  const float* W_ih_b  = (const float*)d_in[6];
  const float* W_hh_b  = (const float*)d_in[7];
  const float* b_b     = (const float*)d_in[8];
  const float* W_emit  = (const float*)d_in[9];
  const float* b_emit  = (const float*)d_in[10];
  const float* trans   = (const float*)d_in[11];
  float* out = (float*)d_out;
  (void)in_sizes; (void)n_in; (void)out_size; (void)ws_size;

  char* ws = (char*)d_ws;
  unsigned short* A    = (unsigned short*)ws; ws += 16777216;   // 2 x 4096 x 1024 bf16
  unsigned short* Wp   = (unsigned short*)ws; ws += 16777216;   // 2 x 4096 x 1024 bf16
  unsigned short* WF   = (unsigned short*)ws; ws += 16777216;   // MFMA-frag-ordered W_hh
  unsigned short* P    = (unsigned short*)ws; ws += 67108864;   // 2 x 4096 x 4096 bf16
  float* h_seq = (float*)ws; ws += 33554432;                    // 2 x 512 x 8 x 1024 f32
  uint*  hg    = (uint*)ws;  ws += 131072;                      // 2buf x 2dir x 8192 u32 tagged
  float* emit  = (float*)ws; ws += 262144;
  float* WET   = (float*)ws; ws += 131072;

  // hg must be zeroed each launch: stale tags from a previous replay could alias
  // this run's tag sequence and let a consumer accept prior-run h values.
  hipMemsetAsync(hg, 0, 131072, stream);
  k_build_A<<<8192, 256, 0, stream>>>(x, lengths, A);
  k_cast_wih<<<8192, 256, 0, stream>>>(W_ih_f, W_ih_b, Wp);
  k_build_wf<<<4096, 256, 0, stream>>>(W_hh_f, W_hh_b, WF);
  k_build_wet<<<128, 256, 0, stream>>>(W_emit, WET);
  k_proj<<<dim3(32, 32, 2), 256, 0, stream>>>(A, Wp, b_f, b_b, P);

  {
    const unsigned short* wf = WF;
    const unsigned short* pp = P;
    const int* ll = lengths;
    uint* hgp = hg; float* hs = h_seq;
    void* args[] = { &wf, &pp, &ll, &hgp, &hs };
    hipLaunchCooperativeKernel((const void*)k_rec, dim3(256), dim3(256),
                               args, 0, stream);
  }

  k_emit<<<1024, 64, 0, stream>>>(h_seq, WET, b_emit, lengths, emit);
  k_crf<<<1, 128, 0, stream>>>(emit, tags, lengths, trans, out);
}